// Round 5
// baseline (151.181 us; speedup 1.0000x reference)
//
#include <hip/hip_runtime.h>
#include <math.h>

#define NCELLS 200000
#define BATCH  8192
#define KNEI   30
#define LATENT 256
#define NDIST  60
#define SLOTS  64   // max refs per z-row; P(Poisson(2.5) > 64) ~ 1e-60

// ---------------- K1: zero counters + gather z_i table (8 MB) ----------------
__global__ __launch_bounds__(256) void k1_prep(
    const float* __restrict__ z_all, const int* __restrict__ cell,
    float* __restrict__ zb, unsigned* __restrict__ cnt)
{
    const int blk = blockIdx.x;
    if (blk < BATCH / 4) {
        const int wave = threadIdx.x >> 6, lane = threadIdx.x & 63;
        const int b  = blk * 4 + wave;
        const int ci = cell[b];
        const float4 v = reinterpret_cast<const float4*>(z_all + (size_t)ci * LATENT)[lane];
        reinterpret_cast<float4*>(zb + (size_t)b * LATENT)[lane] = v;
    } else {
        const int i = (blk - BATCH / 4) * 256 + threadIdx.x;
        if (i < NCELLS) cnt[i] = 0u;
    }
}

// ---------------- K2: scatter-build inverted index ----------------
__global__ __launch_bounds__(256) void k2_scatter(
    const int* __restrict__ knn, const int* __restrict__ cell,
    const int* __restrict__ neg,
    unsigned* __restrict__ cnt, unsigned* __restrict__ inv)
{
    const int t = blockIdx.x * 256 + threadIdx.x;   // t = b*64 + k
    const int b = t >> 6, k = t & 63;
    if (k >= NDIST) return;
    const int idx = (k < KNEI) ? knn[(size_t)cell[b] * KNEI + k]
                               : neg[(size_t)b * KNEI + (k - KNEI)];
    const unsigned pos = atomicAdd(&cnt[idx], 1u);
    if (pos < SLOTS) inv[(size_t)idx * SLOTS + pos] = (unsigned)(b * 64 + k);
}

// ---------------- K3: stream z_all sequentially; push distances ----------------
__global__ __launch_bounds__(256) void k3_dist(
    const float* __restrict__ z_all, const float* __restrict__ zb,
    const unsigned* __restrict__ cnt, const unsigned* __restrict__ inv,
    float* __restrict__ dmat)
{
    const int wave = threadIdx.x >> 6, lane = threadIdx.x & 63;
    const int row  = blockIdx.x * 4 + wave;
    if (row >= NCELLS) return;

    unsigned n = cnt[row];
    if (n == 0) return;            // untouched row: skip (no z read)
    if (n > SLOTS) n = SLOTS;

    const float4 zr = reinterpret_cast<const float4*>(z_all + (size_t)row * LATENT)[lane];

    for (unsigned r = 0; r < n; ++r) {
        const unsigned pid = inv[(size_t)row * SLOTS + r];   // uniform broadcast load
        const int b = pid >> 6, k = pid & 63;
        const float4 v = reinterpret_cast<const float4*>(zb + (size_t)b * LATENT)[lane];
        const float dx = v.x - zr.x;
        const float dy = v.y - zr.y;
        const float dz = v.z - zr.z;
        const float dw = v.w - zr.w;
        float s = dx * dx + dy * dy + dz * dz + dw * dw;

        #pragma unroll
        for (int off = 32; off > 0; off >>= 1)
            s += __shfl_xor(s, off, 64);

        if (lane == 0) dmat[(size_t)b * 64 + k] = sqrtf(s);
    }
}

// ---------------- K4: per-element in-wave softmax -> loss ----------------
__global__ __launch_bounds__(256) void k4_softmax(
    const float* __restrict__ dmat, float* __restrict__ losses)
{
    const int wave = threadIdx.x >> 6, lane = threadIdx.x & 63;
    const int b = blockIdx.x * 4 + wave;

    // lanes 0..29 -> k=lane (knn); lanes 32..61 -> k=lane-2 (neg); rest idle
    const bool act = (lane < KNEI) || (lane >= 32 && lane < 32 + KNEI);
    const int  k   = (lane < 32) ? lane : lane - 2;
    const float sc = act ? -dmat[(size_t)b * 64 + k] : -INFINITY;

    float m = sc;
    #pragma unroll
    for (int off = 32; off > 0; off >>= 1)
        m = fmaxf(m, __shfl_xor(m, off, 64));

    const float e = act ? expf(sc - m) : 0.0f;
    float tot = e;
    float top = (lane < KNEI) ? e : 0.0f;
    #pragma unroll
    for (int off = 32; off > 0; off >>= 1) {
        tot += __shfl_xor(tot, off, 64);
        top += __shfl_xor(top, off, 64);
    }

    if (lane == 0)
        losses[b] = -logf(top / tot + 1e-8f);
}

// ---------------- K5: deterministic mean ----------------
__global__ __launch_bounds__(1024) void k5_reduce(
    const float* __restrict__ losses, float* __restrict__ out)
{
    const int tid  = threadIdx.x;
    const int wave = tid >> 6;
    const int lane = tid & 63;

    float s = 0.0f;
    for (int i = tid; i < BATCH; i += 1024)
        s += losses[i];

    #pragma unroll
    for (int off = 32; off > 0; off >>= 1)
        s += __shfl_xor(s, off, 64);

    __shared__ float buf[16];
    if (lane == 0) buf[wave] = s;
    __syncthreads();

    if (tid == 0) {
        float t = 0.0f;
        #pragma unroll
        for (int i = 0; i < 16; ++i) t += buf[i];
        out[0] = t / (float)BATCH;
    }
}

extern "C" void kernel_launch(void* const* d_in, const int* in_sizes, int n_in,
                              void* d_out, int out_size, void* d_ws, size_t ws_size,
                              hipStream_t stream) {
    const float* z_all = (const float*)d_in[0];
    const int*   knn   = (const int*)d_in[1];
    const int*   cell  = (const int*)d_in[2];
    const int*   neg   = (const int*)d_in[3];
    float* out = (float*)d_out;

    // workspace layout (byte offsets)
    char* ws = (char*)d_ws;
    float*    zb     = (float*)(ws);                        //  8 MB
    unsigned* cnt    = (unsigned*)(ws + (8u << 20));        //  0.8 MB
    unsigned* inv    = (unsigned*)(ws + (16u << 20));       // 51.2 MB
    float*    dmat   = (float*)(ws + (72u << 20));          //  2 MB
    float*    losses = (float*)(ws + (80u << 20));          // 32 KB

    const int k1_grid = BATCH / 4 + (NCELLS + 255) / 256;   // 2048 + 782
    k1_prep   <<<k1_grid,            256, 0, stream>>>(z_all, cell, zb, cnt);
    k2_scatter<<<BATCH * 64 / 256,   256, 0, stream>>>(knn, cell, neg, cnt, inv);
    k3_dist   <<<(NCELLS + 3) / 4,   256, 0, stream>>>(z_all, zb, cnt, inv, dmat);
    k4_softmax<<<BATCH / 4,          256, 0, stream>>>(dmat, losses);
    k5_reduce <<<1,                 1024, 0, stream>>>(losses, out);
}

// Round 6
// 150.448 us; speedup vs baseline: 1.0049x; 1.0049x over previous
//
#include <hip/hip_runtime.h>
#include <math.h>

#define BATCH  8192
#define KNEI   30
#define LATENT 256
#define NDIST  60
#define CHUNK  10
#define NCHUNK (NDIST / CHUNK)
#define GRID   (BATCH / 4)   // 4 waves = 4 batch elements per 256-thread block

// One wave (64 lanes) per batch element; no LDS/barriers in the main path.
// The last block to finish reduces the 8192 losses in a FIXED order
// (deterministic across replays) and writes the mean.
__global__ __launch_bounds__(256) void softnp_fused_kernel(
    const float* __restrict__ z_all,
    const int* __restrict__ knn,       // (N, K) int32
    const int* __restrict__ cell,      // (B,)
    const int* __restrict__ neg,       // (B, K)
    float* __restrict__ losses,        // (B,) scratch
    unsigned* __restrict__ done,       // 1 counter, zeroed via memsetAsync
    float* __restrict__ out)           // final mean
{
    const int tid  = threadIdx.x;
    const int wave = tid >> 6;
    const int lane = tid & 63;
    const int b    = blockIdx.x * 4 + wave;

    const int ci = cell[b];

    // This lane's float4 slice of z_i (register-resident for all 60 pairs)
    const float4 zv = reinterpret_cast<const float4*>(z_all + (size_t)ci * LATENT)[lane];

    // One coalesced index epoch: lanes 0..29 -> knn, lanes 32..61 -> neg.
    int myidx = 0;
    if (lane < KNEI)
        myidx = knn[(size_t)ci * KNEI + lane];
    else if (lane >= 32 && lane < 32 + KNEI)
        myidx = neg[(size_t)b * KNEI + (lane - 32)];

    float dreg = -INFINITY;   // -dist for this lane's candidate; -inf -> exp()=0

    #pragma unroll
    for (int c = 0; c < NCHUNK; ++c) {
        // issue CHUNK independent 1 KB coalesced row gathers
        float4 v[CHUNK];
        #pragma unroll
        for (int j = 0; j < CHUNK; ++j) {
            const int k   = c * CHUNK + j;
            const int src = (k < KNEI) ? k : k + 2;        // skip lanes 30,31
            const int idx = __shfl(myidx, src, 64);
            v[j] = reinterpret_cast<const float4*>(z_all + (size_t)idx * LATENT)[lane];
        }

        float s[CHUNK];
        #pragma unroll
        for (int j = 0; j < CHUNK; ++j) {
            const float dx = v[j].x - zv.x;
            const float dy = v[j].y - zv.y;
            const float dz = v[j].z - zv.z;
            const float dw = v[j].w - zv.w;
            s[j] = dx * dx + dy * dy + dz * dz + dw * dw;
        }

        // batched xor-butterfly (stages pipeline across 10 independent values)
        #pragma unroll
        for (int off = 32; off > 0; off >>= 1) {
            #pragma unroll
            for (int j = 0; j < CHUNK; ++j)
                s[j] += __shfl_xor(s[j], off, 64);
        }

        #pragma unroll
        for (int j = 0; j < CHUNK; ++j) {
            const int k   = c * CHUNK + j;
            const int src = (k < KNEI) ? k : k + 2;
            if (lane == src) dreg = -sqrtf(s[j]);
        }
    }

    // in-wave softmax over -dist (TEMPERATURE == 1)
    float m = dreg;
    #pragma unroll
    for (int off = 32; off > 0; off >>= 1)
        m = fmaxf(m, __shfl_xor(m, off, 64));

    const float e = expf(dreg - m);
    float tot = e;
    float top = (lane < KNEI) ? e : 0.0f;
    #pragma unroll
    for (int off = 32; off > 0; off >>= 1) {
        tot += __shfl_xor(tot, off, 64);
        top += __shfl_xor(top, off, 64);
    }

    if (lane == 0)
        losses[b] = -logf(top / tot + 1e-8f);

    // ---- last-block fused mean (deterministic fixed-order reduction) ----
    __shared__ bool amLast;
    __syncthreads();                      // all 4 losses of this block written
    if (tid == 0) {
        __threadfence();                  // make losses visible device-wide
        amLast = (atomicAdd(done, 1u) == GRID - 1u);
    }
    __syncthreads();

    if (amLast) {
        __threadfence();                  // acquire: see all blocks' losses
        float s = 0.0f;
        for (int i = tid; i < BATCH; i += 256)   // fixed per-thread order
            s += losses[i];
        #pragma unroll
        for (int off = 32; off > 0; off >>= 1)
            s += __shfl_xor(s, off, 64);

        __shared__ float buf[4];
        if (lane == 0) buf[wave] = s;
        __syncthreads();
        if (tid == 0)
            out[0] = (buf[0] + buf[1] + buf[2] + buf[3]) / (float)BATCH;
    }
}

extern "C" void kernel_launch(void* const* d_in, const int* in_sizes, int n_in,
                              void* d_out, int out_size, void* d_ws, size_t ws_size,
                              hipStream_t stream) {
    const float* z_all = (const float*)d_in[0];
    const int*   knn   = (const int*)d_in[1];
    const int*   cell  = (const int*)d_in[2];
    const int*   neg   = (const int*)d_in[3];
    float* out = (float*)d_out;

    unsigned* done   = (unsigned*)d_ws;                 // 4 B counter
    float*    losses = (float*)((char*)d_ws + 256);     // BATCH floats

    hipMemsetAsync(done, 0, sizeof(unsigned), stream);  // graph-legal
    softnp_fused_kernel<<<GRID, 256, 0, stream>>>(z_all, knn, cell, neg,
                                                  losses, done, out);
}

// Round 7
// 83.471 us; speedup vs baseline: 1.8112x; 1.8024x over previous
//
#include <hip/hip_runtime.h>
#include <math.h>

#define BATCH  8192
#define KNEI   30
#define LATENT 256
#define NDIST  60            // 2*K
#define ROWS_PER_WAVE 15     // NDIST / 4 waves

// One block (256 threads, 4 waves) per batch element.
__global__ __launch_bounds__(256) void softnp_dist_kernel(
    const float* __restrict__ z_all,
    const int* __restrict__ knn,       // (N, K) int32
    const int* __restrict__ cell,      // (B,)
    const int* __restrict__ neg,       // (B, K)
    float* __restrict__ losses)        // (B,)
{
    const int b    = blockIdx.x;
    const int tid  = threadIdx.x;
    const int wave = tid >> 6;
    const int lane = tid & 63;

    __shared__ float dist[NDIST + 4];

    const int ci = cell[b];

    // Each lane's float4 slice of z_i; all 4 waves read the same 1 KB row
    // (L1/L2 broadcast) - no LDS round trip, no extra barrier.
    const float4 zv = reinterpret_cast<const float4*>(z_all + (size_t)ci * LATENT)[lane];

    // ---- load all 15 wave-uniform indices ----
    int idx[ROWS_PER_WAVE];
    #pragma unroll
    for (int j = 0; j < ROWS_PER_WAVE; ++j) {
        const int k = wave + 4 * j;
        idx[j] = (k < KNEI) ? knn[(size_t)ci * KNEI + k]
                            : neg[(size_t)b * KNEI + (k - KNEI)];
    }

    // ---- issue all 15 gathers (1 KB coalesced each) up-front ----
    float4 v[ROWS_PER_WAVE];
    #pragma unroll
    for (int j = 0; j < ROWS_PER_WAVE; ++j)
        v[j] = reinterpret_cast<const float4*>(z_all + (size_t)idx[j] * LATENT)[lane];

    // ---- per-lane partial squared distances (independent FMA chains) ----
    float s[ROWS_PER_WAVE];
    #pragma unroll
    for (int j = 0; j < ROWS_PER_WAVE; ++j) {
        const float dx = v[j].x - zv.x;
        const float dy = v[j].y - zv.y;
        const float dz = v[j].z - zv.z;
        const float dw = v[j].w - zv.w;
        s[j] = dx * dx + dy * dy + dz * dz + dw * dw;
    }

    // ---- batched wave reduction: 15 independent values pipeline through
    //      each shuffle stage instead of 15 serial 6-deep chains ----
    #pragma unroll
    for (int off = 32; off > 0; off >>= 1) {
        #pragma unroll
        for (int j = 0; j < ROWS_PER_WAVE; ++j)
            s[j] += __shfl_xor(s[j], off, 64);
    }

    if (lane == 0) {
        #pragma unroll
        for (int j = 0; j < ROWS_PER_WAVE; ++j)
            dist[wave + 4 * j] = sqrtf(s[j]);
    }
    __syncthreads();

    // ---- wave 0: 60-wide softmax over -dist (TEMPERATURE == 1) ----
    if (wave == 0) {
        const float sc = (lane < NDIST) ? -dist[lane] : -INFINITY;

        float m = sc;
        #pragma unroll
        for (int off = 32; off > 0; off >>= 1)
            m = fmaxf(m, __shfl_xor(m, off, 64));

        const float e = (lane < NDIST) ? expf(sc - m) : 0.0f;
        float tot = e;
        float top = (lane < KNEI) ? e : 0.0f;
        #pragma unroll
        for (int off = 32; off > 0; off >>= 1) {
            tot += __shfl_xor(tot, off, 64);
            top += __shfl_xor(top, off, 64);
        }

        if (lane == 0)
            losses[b] = -logf(top / tot + 1e-8f);
    }
}

// Deterministic mean over the 8192 per-element losses.
__global__ __launch_bounds__(1024) void softnp_reduce_kernel(
    const float* __restrict__ losses, float* __restrict__ out)
{
    const int tid  = threadIdx.x;
    const int wave = tid >> 6;
    const int lane = tid & 63;

    float s = 0.0f;
    for (int i = tid; i < BATCH; i += 1024)
        s += losses[i];

    #pragma unroll
    for (int off = 32; off > 0; off >>= 1)
        s += __shfl_xor(s, off, 64);

    __shared__ float buf[16];
    if (lane == 0) buf[wave] = s;
    __syncthreads();

    if (tid == 0) {
        float t = 0.0f;
        #pragma unroll
        for (int i = 0; i < 16; ++i) t += buf[i];
        out[0] = t / (float)BATCH;
    }
}

extern "C" void kernel_launch(void* const* d_in, const int* in_sizes, int n_in,
                              void* d_out, int out_size, void* d_ws, size_t ws_size,
                              hipStream_t stream) {
    const float* z_all = (const float*)d_in[0];
    const int*   knn   = (const int*)d_in[1];
    const int*   cell  = (const int*)d_in[2];
    const int*   neg   = (const int*)d_in[3];
    float* out    = (float*)d_out;
    float* losses = (float*)d_ws;   // BATCH floats of scratch

    softnp_dist_kernel<<<BATCH, 256, 0, stream>>>(z_all, knn, cell, neg, losses);
    softnp_reduce_kernel<<<1, 1024, 0, stream>>>(losses, out);
}